// Round 1
// baseline (198.723 us; speedup 1.0000x reference)
//
#include <hip/hip_runtime.h>

#define HIST_BINS 64
#define NBATCH 128
#define THREADS 256
#define BLOCKS_PER_BATCH 16
#define WAVES_PER_BLOCK (THREADS / 64)

// ---------------------------------------------------------------------------
// Kernel 1: per-batch 64-bin histogram of valid values in [0, 255].
// Grid: (BLOCKS_PER_BATCH, NBATCH). Per-wave LDS histograms to minimize
// atomic contention; one global atomicAdd per bin per block at the end.
// ---------------------------------------------------------------------------
__global__ __launch_bounds__(THREADS) void hist_kernel(
    const float* __restrict__ g, unsigned int* __restrict__ hist, int n_per_batch) {
    __shared__ unsigned int lh[WAVES_PER_BLOCK][HIST_BINS];

    const int tid  = threadIdx.x;
    const int wave = tid >> 6;

    // zero LDS histograms
    for (int i = tid; i < WAVES_PER_BLOCK * HIST_BINS; i += THREADS)
        ((unsigned int*)lh)[i] = 0u;
    __syncthreads();

    const int batch = blockIdx.y;
    const float4* gp = (const float4*)(g + (size_t)batch * (size_t)n_per_batch);
    const int n4 = n_per_batch >> 2;                    // float4 count per batch
    const float scale = 64.0f / 255.0f;                 // matches f32(64/255) in ref

    // grid-stride over this batch's float4s (across BLOCKS_PER_BATCH blocks)
    for (int i = blockIdx.x * THREADS + tid; i < n4; i += BLOCKS_PER_BATCH * THREADS) {
        float4 v = gp[i];
        float vs[4] = {v.x, v.y, v.z, v.w};
#pragma unroll
        for (int j = 0; j < 4; ++j) {
            float val = vs[j];
            if (val >= 0.0f && val <= 255.0f) {
                int idx = (int)floorf(val * scale);
                idx = min(max(idx, 0), HIST_BINS - 1);
                atomicAdd(&lh[wave][idx], 1u);
            }
        }
    }
    __syncthreads();

    if (tid < HIST_BINS) {
        unsigned int s = 0;
#pragma unroll
        for (int w = 0; w < WAVES_PER_BLOCK; ++w) s += lh[w][tid];
        atomicAdd(&hist[batch * HIST_BINS + tid], s);
    }
}

// ---------------------------------------------------------------------------
// Kernel 2: normalize histogram (L1) + MLP: relu(hist @ W1^T + b1) @ W2^T + b2
// One block (128 threads) per batch.
// ---------------------------------------------------------------------------
__global__ __launch_bounds__(128) void mlp_kernel(
    const unsigned int* __restrict__ hist,
    const float* __restrict__ W1, const float* __restrict__ b1,
    const float* __restrict__ W2, const float* __restrict__ b2,
    float* __restrict__ out) {
    __shared__ float hn[HIST_BINS];
    __shared__ float h[32];

    const int b   = blockIdx.x;
    const int tid = threadIdx.x;

    if (tid < HIST_BINS) hn[tid] = (float)hist[b * HIST_BINS + tid];
    __syncthreads();

    // L1 sum: counts are integers <= 2^18, exact in fp32 regardless of order
    float sum = 0.0f;
    for (int i = 0; i < HIST_BINS; ++i) sum += hn[i];
    const float denom = fmaxf(sum, 1e-12f);
    __syncthreads();

    if (tid < HIST_BINS) hn[tid] = hn[tid] / denom;  // divide (match ref rounding)
    __syncthreads();

    if (tid < 32) {
        float acc = b1[tid];
        for (int k = 0; k < HIST_BINS; ++k) acc += hn[k] * W1[tid * HIST_BINS + k];
        h[tid] = fmaxf(acc, 0.0f);
    }
    __syncthreads();

    float acc = b2[tid];
    for (int k = 0; k < 32; ++k) acc += h[k] * W2[tid * 32 + k];
    out[b * 128 + tid] = acc;
}

extern "C" void kernel_launch(void* const* d_in, const int* in_sizes, int n_in,
                              void* d_out, int out_size, void* d_ws, size_t ws_size,
                              hipStream_t stream) {
    const float* g  = (const float*)d_in[0];
    const float* W1 = (const float*)d_in[1];
    const float* b1 = (const float*)d_in[2];
    const float* W2 = (const float*)d_in[3];
    const float* b2 = (const float*)d_in[4];
    float* out = (float*)d_out;

    unsigned int* hist = (unsigned int*)d_ws;
    const int n_per_batch = in_sizes[0] / NBATCH;   // 512*512 = 262144

    // d_ws is poisoned to 0xAA before every timed launch — zero it (capture-safe)
    hipMemsetAsync(hist, 0, NBATCH * HIST_BINS * sizeof(unsigned int), stream);

    hist_kernel<<<dim3(BLOCKS_PER_BATCH, NBATCH), THREADS, 0, stream>>>(g, hist, n_per_batch);
    mlp_kernel<<<NBATCH, 128, 0, stream>>>(hist, W1, b1, W2, b2, out);
}